// Round 1
// baseline (87.169 us; speedup 1.0000x reference)
//
#include <hip/hip_runtime.h>
#include <cstdint>

// CharEmb: per word (B*S=16384): gather 32 char embeddings (E=64) -> x[64][32]
// (raw view of the [32 chars][64] buffer), conv1d(F=128,K=3,valid,T=30), bias,
// max over t. Output float32 [16384][128].
//
// MFMA formulation (32x32x16 bf16), transposed so M=t, N=f:
//   D[t][f] = sum_kk sum_e xT[t+kk][e] * W[f][e][kk]
// - xT[c][e] staged in LDS (bf16), row stride 72 elems (144 B) to balance banks.
// - conv shift t+kk = LDS address offset on the A-fragment read (free).
// - A frag layout: A[m=lane&31][k=(lane>>5)*8+j]  (analog of measured 16x16x32)
// - B frag layout: B[k=(lane>>5)*8+j][n=lane&31]  -> weights pre-packed in ws.
// - C/D layout (measured): col(n)=lane&31, row(m)=(reg&3)+8*(reg>>2)+4*(lane>>5)
// - valid t = 0..29 -> exclude t=30 (reg14,h=1) and t=31 (reg15,h=1) from max.
// - rows 32,33 of xT are never written; they feed only D rows 30,31 (masked).

typedef __bf16 bf16x8 __attribute__((ext_vector_type(8)));
typedef float  f32x16 __attribute__((ext_vector_type(16)));

#define WPB 16   // words per block; 1024 blocks * 16 = 16384 words

// Pack conv_w [F=128][E=64][K=3] fp32 -> B-fragment-ordered bf16 in ws:
// pw[(((nt*3+kk)*4+ks)*64 + lane)*8 + j] = w[f=nt*32+(lane&31)][e=ks*16+(lane>>5)*8+j][kk]
__global__ __launch_bounds__(256)
void prep_pack_w(const float* __restrict__ w, __bf16* __restrict__ pw) {
  int i = blockIdx.x * 256 + threadIdx.x;   // 0..24575
  int j    = i & 7;
  int lane = (i >> 3) & 63;
  int ks   = (i >> 9) & 3;
  int t    = i >> 11;        // nt*3 + kk
  int kk   = t % 3;
  int nt   = t / 3;
  int f = nt * 32 + (lane & 31);
  int e = ks * 16 + (lane >> 5) * 8 + j;
  pw[i] = (__bf16)w[f * 192 + e * 3 + kk];
}

__global__ __launch_bounds__(256)
void charcnn_mfma(const int* __restrict__ cid, const float* __restrict__ emb,
                  const float* __restrict__ bias, const __bf16* __restrict__ pw,
                  float* __restrict__ out) {
  // xT: 36 rows (rows 0..31 written; 32,33 read-as-garbage for masked t) x 72 cols
  __shared__ __align__(16) __bf16 xT[2][36 * 72];

  const int tid  = threadIdx.x;
  const int lane = tid & 63;
  const int wv   = tid >> 6;          // wave id == N-tile (f block of 32)

  // persistent B fragments (weights), 12 frags = 48 VGPRs
  bf16x8 bfrag[12];
  const bf16x8* pwv = (const bf16x8*)pw;
#pragma unroll
  for (int q = 0; q < 12; ++q)        // q = kk*4 + ks
    bfrag[q] = pwv[(wv * 12 + q) * 64 + lane];

  const float vb = bias[wv * 32 + (lane & 31)];

  // staging map: thread -> (char slot a, float4 pair p)
  const int a  = tid >> 3;            // 0..31
  const int p  = tid & 7;             // 0..7
  const int d0 = p * 4;               // row base (c = d0..d0+3)
  const int bw = blockIdx.x * WPB;

  // stage word w into LDS buffer buf:
  // xT[c][2a]   = emb[ch[a]][c]      (c = 0..31)
  // xT[c][2a+1] = emb[ch[a]][32+c]
  auto stage = [&](int w, int buf) {
    int ch = cid[(bw + w) * 32 + a];
    const float4* er = (const float4*)(emb + ch * 64);
    float4 lo = er[p];         // d = d0..d0+3
    float4 hi = er[p + 8];     // d = d0+32..d0+35
    uint32_t* dst = (uint32_t*)(&xT[buf][0]);
    float lv[4] = {lo.x, lo.y, lo.z, lo.w};
    float hv[4] = {hi.x, hi.y, hi.z, hi.w};
#pragma unroll
    for (int i2 = 0; i2 < 4; ++i2) {
      uint32_t u = ((uint32_t)__builtin_bit_cast(uint16_t, (__bf16)hv[i2]) << 16)
                 |  (uint32_t)__builtin_bit_cast(uint16_t, (__bf16)lv[i2]);
      dst[(d0 + i2) * 36 + a] = u;   // dword index: row*36 + colpair
    }
  };

  stage(0, 0);
  __syncthreads();

  for (int w = 0; w < WPB; ++w) {
    if (w + 1 < WPB) stage(w + 1, (w + 1) & 1);

    const __bf16* xb = &xT[w & 1][0];
    f32x16 acc;
#pragma unroll
    for (int i2 = 0; i2 < 16; ++i2) acc[i2] = 0.0f;

#pragma unroll
    for (int kk = 0; kk < 3; ++kk) {
#pragma unroll
      for (int ks = 0; ks < 4; ++ks) {
        // A[m][k] = xT[m+kk][ks*16 + (lane>>5)*8 + j], m = lane&31
        const bf16x8* ap = (const bf16x8*)(xb + ((lane & 31) + kk) * 72
                                              + ks * 16 + (lane >> 5) * 8);
        acc = __builtin_amdgcn_mfma_f32_32x32x16_bf16(*ap, bfrag[kk * 4 + ks],
                                                      acc, 0, 0, 0);
      }
    }

    // epilogue: max over t.  t = (reg&3) + 8*(reg>>2) + 4*(lane>>5).
    // upper half (lane>=32): regs 14,15 are t=30,31 -> excluded.
    float m0 = acc[0];
#pragma unroll
    for (int r = 1; r <= 13; ++r) m0 = fmaxf(m0, acc[r]);
    float m1 = fmaxf(acc[14], acc[15]);
    float mm = (lane < 32) ? fmaxf(m0, m1) : m0;
    float other = __shfl_xor(mm, 32, 64);
    float fullmax = fmaxf(mm, other) + vb;
    if (lane < 32) out[(bw + w) * 128 + wv * 32 + lane] = fullmax;

    __syncthreads();
  }
}

extern "C" void kernel_launch(void* const* d_in, const int* in_sizes, int n_in,
                              void* d_out, int out_size, void* d_ws, size_t ws_size,
                              hipStream_t stream) {
  const int*   cid = (const int*)d_in[0];    // [32*512*32] int32
  const float* emb = (const float*)d_in[1];  // [101*64]  f32
  const float* cw  = (const float*)d_in[2];  // [128*64*3] f32
  const float* cb  = (const float*)d_in[3];  // [128] f32
  float* outp = (float*)d_out;               // [16384*128] f32
  __bf16* pw = (__bf16*)d_ws;                // 24576 bf16 = 48 KB

  hipLaunchKernelGGL(prep_pack_w, dim3(96), dim3(256), 0, stream, cw, pw);
  hipLaunchKernelGGL(charcnn_mfma, dim3(1024), dim3(256), 0, stream,
                     cid, emb, cb, (const __bf16*)pw, outp);
}

// Round 2
// 85.500 us; speedup vs baseline: 1.0195x; 1.0195x over previous
//
#include <hip/hip_runtime.h>
#include <cstdint>

// CharEmb: per word (B*S=16384): gather 32 char embeddings (E=64) -> x[64][32]
// (raw view of the [32 chars][64] buffer), conv1d(F=128,K=3,valid,T=30), bias,
// max over t. Output float32 [16384][128].
//
// MFMA formulation (32x32x16 bf16), M=t, N=f (VERIFIED round 1, absmax 0.031):
//   D[t][f] = sum_kk sum_e xT[t+kk][e] * W[f][e][kk]
// - xT[c][e] staged in LDS bf16, row stride 72 elems (144 B, 16B-aligned).
// - conv shift t+kk = pure LDS address offset on the A-fragment read.
// - A frag: A[m=lane&31][k=(lane>>5)*8+j]; B frag: B[k][n=lane&31] (pre-packed).
// - C/D: col=lane&31, row=(reg&3)+8*(reg>>2)+4*(lane>>5); t=30,31 masked.
//
// Round 2: grouped double-buffered staging. GW=4 words per barrier (was 1),
// cid loads batched ahead of emb gathers, 34-row buffers (rows 32,33 garbage,
// feed only masked t=30,31), 8 buffers = 39168 B LDS -> 4 blocks/CU.

typedef __bf16 bf16x8 __attribute__((ext_vector_type(8)));
typedef float  f32x16 __attribute__((ext_vector_type(16)));

#define GW   4    // words staged per barrier group
#define NGRP 4    // groups per block; 16 words/block, 1024 blocks
#define ROWS 34
#define RST  72   // row stride in bf16 elems (36 dwords)

// Pack conv_w [F=128][E=64][K=3] fp32 -> B-fragment-ordered bf16 in ws:
// pw[(((nt*3+kk)*4+ks)*64 + lane)*8 + j] = w[f=nt*32+(lane&31)][e=ks*16+(lane>>5)*8+j][kk]
__global__ __launch_bounds__(256)
void prep_pack_w(const float* __restrict__ w, __bf16* __restrict__ pw) {
  int i = blockIdx.x * 256 + threadIdx.x;   // 0..24575
  int j    = i & 7;
  int lane = (i >> 3) & 63;
  int ks   = (i >> 9) & 3;
  int t    = i >> 11;        // nt*3 + kk
  int kk   = t % 3;
  int nt   = t / 3;
  int f = nt * 32 + (lane & 31);
  int e = ks * 16 + (lane >> 5) * 8 + j;
  pw[i] = (__bf16)w[f * 192 + e * 3 + kk];
}

__global__ __launch_bounds__(256, 4)
void charcnn_mfma(const int* __restrict__ cid, const float* __restrict__ emb,
                  const float* __restrict__ bias, const __bf16* __restrict__ pw,
                  float* __restrict__ out) {
  // 8 word-buffers (two groups of 4), 34 rows x 72 bf16 = 4896 B each.
  __shared__ __align__(16) __bf16 xT[8][ROWS * RST];

  const int tid  = threadIdx.x;
  const int lane = tid & 63;
  const int wv   = tid >> 6;          // wave id == N-tile (f block of 32)

  // persistent B fragments (weights), 12 frags = 48 VGPRs
  bf16x8 bfrag[12];
  const bf16x8* pwv = (const bf16x8*)pw;
#pragma unroll
  for (int q = 0; q < 12; ++q)        // q = kk*4 + ks
    bfrag[q] = pwv[(wv * 12 + q) * 64 + lane];

  const float vb = bias[wv * 32 + (lane & 31)];

  // staging map: thread -> (char slot a, float4 pair p)
  const int a  = tid >> 3;            // 0..31 (char within word)
  const int p  = tid & 7;             // 0..7  (float4 index)
  const int d0 = p * 4;               // row base (c = d0..d0+3)
  const int bw = blockIdx.x * (GW * NGRP);

  // stage 4 words of group g: xT[c][2a]=emb[ch[a]][c], xT[c][2a+1]=emb[ch[a]][32+c]
  auto stage_group = [&](int g) {
    const int w0 = g * GW;
    int ch[GW];
#pragma unroll
    for (int i = 0; i < GW; ++i)
      ch[i] = cid[(bw + w0 + i) * 32 + a];
#pragma unroll
    for (int i = 0; i < GW; ++i) {
      const float4* er = (const float4*)(emb + ch[i] * 64);
      float4 lo = er[p];         // c = d0..d0+3
      float4 hi = er[p + 8];     // c = d0..d0+3, upper 32 dims
      uint32_t* dst = (uint32_t*)(&xT[(w0 + i) & 7][0]);
      float lv[4] = {lo.x, lo.y, lo.z, lo.w};
      float hv[4] = {hi.x, hi.y, hi.z, hi.w};
#pragma unroll
      for (int i2 = 0; i2 < 4; ++i2) {
        uint32_t u = ((uint32_t)__builtin_bit_cast(uint16_t, (__bf16)hv[i2]) << 16)
                   |  (uint32_t)__builtin_bit_cast(uint16_t, (__bf16)lv[i2]);
        dst[(d0 + i2) * 36 + a] = u;   // dword index: row*36 + colpair
      }
    }
  };

  auto compute_word = [&](int w) {
    const __bf16* xb = &xT[w & 7][0];
    f32x16 acc;
#pragma unroll
    for (int i2 = 0; i2 < 16; ++i2) acc[i2] = 0.0f;

#pragma unroll
    for (int kk = 0; kk < 3; ++kk) {
#pragma unroll
      for (int ks = 0; ks < 4; ++ks) {
        // A[m][k] = xT[m+kk][ks*16 + (lane>>5)*8 + j], m = lane&31
        const bf16x8* ap = (const bf16x8*)(xb + ((lane & 31) + kk) * RST
                                              + ks * 16 + (lane >> 5) * 8);
        acc = __builtin_amdgcn_mfma_f32_32x32x16_bf16(*ap, bfrag[kk * 4 + ks],
                                                      acc, 0, 0, 0);
      }
    }

    // max over t. t = (reg&3) + 8*(reg>>2) + 4*(lane>>5).
    // upper half (lane>=32): regs 14,15 are t=30,31 -> excluded.
    float m0 = acc[0];
#pragma unroll
    for (int r = 1; r <= 13; ++r) m0 = fmaxf(m0, acc[r]);
    float m1 = fmaxf(acc[14], acc[15]);
    float mm = (lane < 32) ? fmaxf(m0, m1) : m0;
    float other = __shfl_xor(mm, 32, 64);
    float fullmax = fmaxf(mm, other) + vb;
    if (lane < 32) out[(bw + w) * 128 + wv * 32 + lane] = fullmax;
  };

  stage_group(0);
  __syncthreads();

  for (int g = 0; g < NGRP; ++g) {
    if (g + 1 < NGRP) stage_group(g + 1);   // global loads issue early
    const int w0 = g * GW;
#pragma unroll
    for (int i = 0; i < GW; ++i) compute_word(w0 + i);
    __syncthreads();
  }
}

extern "C" void kernel_launch(void* const* d_in, const int* in_sizes, int n_in,
                              void* d_out, int out_size, void* d_ws, size_t ws_size,
                              hipStream_t stream) {
  const int*   cid = (const int*)d_in[0];    // [32*512*32] int32
  const float* emb = (const float*)d_in[1];  // [101*64]  f32
  const float* cw  = (const float*)d_in[2];  // [128*64*3] f32
  const float* cb  = (const float*)d_in[3];  // [128] f32
  float* outp = (float*)d_out;               // [16384*128] f32
  __bf16* pw = (__bf16*)d_ws;                // 24576 bf16 = 48 KB

  hipLaunchKernelGGL(prep_pack_w, dim3(96), dim3(256), 0, stream, cw, pw);
  hipLaunchKernelGGL(charcnn_mfma, dim3(1024), dim3(256), 0, stream,
                     cid, emb, cb, (const __bf16*)pw, outp);
}